// Round 23
// baseline (449.361 us; speedup 1.0000x reference)
//
#include <hip/hip_runtime.h>
#include <hip/hip_bf16.h>

#define B_SZ   1024
#define T_SZ   64
#define D_IN   1662
#define D_INP  1664                 // padded to 32-multiple
#define M_SZ   (B_SZ * T_SZ)        // 65536

typedef __attribute__((ext_vector_type(8))) short short8;
typedef __attribute__((ext_vector_type(4))) float f32x4;
typedef unsigned short ushort_t;

// fp32 -> bf16 round-to-nearest-even (finite inputs)
__device__ __forceinline__ unsigned short f2bf(float f) {
    unsigned u = __builtin_bit_cast(unsigned, f);
    u += 0x7FFFu + ((u >> 16) & 1u);
    return (unsigned short)(u >> 16);
}
__device__ __forceinline__ float bf2f(ushort_t u) {
    return __builtin_bit_cast(float, (unsigned)u << 16);
}

// async global->LDS, 16B per lane, dest = wave-uniform base + lane*16
#define GLD16(gp, lp) __builtin_amdgcn_global_load_lds(                        \
    (const __attribute__((address_space(1))) void*)(gp),                       \
    (__attribute__((address_space(3))) void*)(lp), 16, 0, 0)

__device__ __forceinline__ float sigmoid_f(float x) {
    return 1.0f / (1.0f + __expf(-x));
}
__device__ __forceinline__ float tanh_f(float x) {
    float a = fabsf(x);
    float e = __expf(2.0f * a);
    float r = 1.0f - 2.0f / (e + 1.0f);
    return copysignf(r, x);
}

// ---------------------------------------------------------------------------
// convert fp32 [256,1662] -> bf16 [256,1664] (w_ih1 only; zero-pads cols)
// ---------------------------------------------------------------------------
__global__ __launch_bounds__(256) void convert_w1(
    const float* __restrict__ src, ushort_t* __restrict__ dst)
{
    constexpr int cpr = D_INP >> 3;
    const int total = 256 * cpr;
    const int stride = gridDim.x * blockDim.x;
    for (int idx = blockIdx.x * blockDim.x + threadIdx.x;
         idx < total; idx += stride) {
        const int row  = idx / cpr;
        const int base = (idx % cpr) << 3;
        const float* s = src + (size_t)row * D_IN;
        short8 o;
        #pragma unroll
        for (int j = 0; j < 4; ++j) {
            const int k = base + 2 * j;
            float2 v = make_float2(0.f, 0.f);
            if (k < D_IN) v = *(const float2*)(s + k);
            o[2 * j]     = (short)f2bf(v.x);
            o[2 * j + 1] = (short)f2bf(v.y);
        }
        *(short8*)(dst + (size_t)row * D_INP + base) = o;
    }
}

// ---------------------------------------------------------------------------
// Layer-1 GEMM — BM=128 (r20/r22 best-known configuration, unchanged):
// out[M,256]bf16 = A[M,K]fp32 @ W[256,Kp]bf16^T.
// 128x256 tile, BK=32, 512 threads (8 waves, 2x4), grid M/128=512 ->
// 2 blocks/CU. Per iteration each block stages W ONCE for 128 M-rows.
// ---------------------------------------------------------------------------
__global__ __launch_bounds__(512, 2) void gemm_l1(
    const float* __restrict__ A, const ushort_t* __restrict__ W,
    ushort_t* __restrict__ out)
{
    constexpr int K = D_IN, Kp = D_INP, G = 256;
    __shared__ __align__(16) ushort_t As[128 * 32];     //  8 KB
    __shared__ __align__(16) ushort_t Ws[256 * 32];     // 16 KB

    const int tid = threadIdx.x, lane = tid & 63, wid = tid >> 6;
    const int wr = wid >> 2, wc = wid & 3;        // 2x4 wave grid
    const int m0 = blockIdx.x * 128;

    // A staging: row tid>>2 (0..127), 8 fp32 (4x float2) at col (tid&3)*8
    const int arow  = tid >> 2;
    const int acolb = (tid & 3) * 8;
    const float* Abase = A + (size_t)(m0 + arow) * K + acolb;

    // W staging: wave wid stages rows wid*32..+31 in 2 GLD16 chunks of 16
    const size_t wlofs = (size_t)(lane >> 2) * Kp + (lane & 3) * 8;
    const ushort_t* Wg0 = W + (size_t)(wid * 32) * Kp + wlofs;
    const ushort_t* Wg1 = Wg0 + (size_t)16 * Kp;
    ushort_t* lw0 = &Ws[(wid * 32) * 32];
    ushort_t* lw1 = lw0 + 16 * 32;

    const int fr = lane & 15, kq = (lane >> 4) * 8;

    f32x4 acc[4][4] = {};
    const int nFull = K / 32;                 // 51 full iters + 1 tail

    float2 av[4];
    #pragma unroll
    for (int j = 0; j < 4; ++j) av[j] = *(const float2*)(Abase + 2 * j);

    for (int it = 0; it <= nFull; ++it) {
        const int k0 = it * 32;
        __syncthreads();                      // prev iter LDS reads done
        GLD16(Wg0 + k0, lw0); GLD16(Wg1 + k0, lw1);
        short8 pk;
        #pragma unroll
        for (int j = 0; j < 4; ++j) {
            pk[2 * j]     = (short)f2bf(av[j].x);
            pk[2 * j + 1] = (short)f2bf(av[j].y);
        }
        *(short8*)&As[arow * 32 + acolb] = pk;
        __syncthreads();                      // staging (incl vmcnt) done

        // prefetch A for it+1 (hides under MFMA below)
        if (it < nFull) {
            const int kn = (it + 1) * 32;
            if (it + 1 < nFull) {
                #pragma unroll
                for (int j = 0; j < 4; ++j)
                    av[j] = *(const float2*)(Abase + kn + 2 * j);
            } else {
                #pragma unroll
                for (int j = 0; j < 4; ++j) {
                    const int kk = kn + acolb + 2 * j;
                    av[j] = (kk < K) ? *(const float2*)(Abase + kn + 2 * j)
                                     : make_float2(0.f, 0.f);
                }
            }
        }

        short8 af[4], bfr[4];
        #pragma unroll
        for (int fm = 0; fm < 4; ++fm)
            af[fm] = *(const short8*)&As[(wr * 64 + fm * 16 + fr) * 32 + kq];
        #pragma unroll
        for (int fn = 0; fn < 4; ++fn)
            bfr[fn] = *(const short8*)&Ws[(wc * 64 + fn * 16 + fr) * 32 + kq];
        #pragma unroll
        for (int fm = 0; fm < 4; ++fm)
            #pragma unroll
            for (int fn = 0; fn < 4; ++fn)
                acc[fm][fn] = __builtin_amdgcn_mfma_f32_16x16x32_bf16(
                    af[fm], bfr[fn], acc[fm][fn], 0, 0, 0);
    }

    // epilogue: bf16, no bias. C/D: col=lane&15, row=(lane>>4)*4+j
    const int rbase = (lane >> 4) * 4;
    #pragma unroll
    for (int fn = 0; fn < 4; ++fn) {
        const int g = wc * 64 + fn * 16 + fr;
        #pragma unroll
        for (int fm = 0; fm < 4; ++fm) {
            const int mbase = m0 + wr * 64 + fm * 16 + rbase;
            #pragma unroll
            for (int j = 0; j < 4; ++j)
                out[(size_t)(mbase + j) * G + g] = f2bf(acc[fm][fn][j]);
        }
    }
}

// ---------------------------------------------------------------------------
// Pipelined 3-layer LSTM, gate-grouped, one barrier per step.
// NOW 2 batch rows/block, grid B/2 = 512 -> 2 BLOCKS/CU: two independent
// serial chains interleave on each CU, hiding each other's barrier/latency
// stalls. Per-batch-row math identical to r14/r22 -> bit-identical output.
// Wave roles: wid 0-1 -> L1 (32 units each), 2-5 -> L2, 6-7 -> L3.
// Cell update: 1 item/thread (row = hi&1, unit tile = hi>>1).
// ---------------------------------------------------------------------------
__global__ __launch_bounds__(512, 2) void lstm3_gg(
    const ushort_t* __restrict__ xg1,   // [B,T,256] bf16 (no bias)
    const float* __restrict__ whh1,
    const float* __restrict__ bih1, const float* __restrict__ bhh1,
    const float* __restrict__ wih2, const float* __restrict__ whh2,
    const float* __restrict__ bih2, const float* __restrict__ bhh2,
    const float* __restrict__ wih3, const float* __restrict__ whh3,
    const float* __restrict__ bih3, const float* __restrict__ bhh3,
    float* __restrict__ hlast, int Tn)  // [B,64]
{
    __shared__ ushort_t h1sh[2][16 * 64];
    __shared__ ushort_t h2sh[2][16 * 128];
    __shared__ ushort_t h3sh[2][16 * 64];
    __shared__ __align__(16) ushort_t xsh[2][512];    // 2 rows x 256
    __shared__ __align__(16) float gsw[8][128 * 4];   // per-wave gate frags

    const int tid = threadIdx.x, lane = tid & 63, wid = tid >> 6;
    const int r0 = blockIdx.x * 2;
    const int fr = lane & 15, hi = lane >> 4, kq = hi * 8;

    int role, ubase, Hl;
    if (wid < 2)      { role = 1; ubase = wid * 32;       Hl = 64; }
    else if (wid < 6) { role = 2; ubase = (wid - 2) * 32; Hl = 128; }
    else              { role = 3; ubase = (wid - 6) * 32; Hl = 64; }

    short8 bregS[2][4][2];
    short8 bregL[2][4][4];
    #pragma unroll
    for (int ut = 0; ut < 2; ++ut)
        #pragma unroll
        for (int g = 0; g < 4; ++g) {
            const int uu = ubase + ut * 16 + fr;
            const float *pS, *pL = nullptr;
            if (role == 1)      { pS = whh1 + (size_t)(g * 64 + uu) * 64; }
            else if (role == 2) { pS = wih2 + (size_t)(g * 128 + uu) * 64;
                                  pL = whh2 + (size_t)(g * 128 + uu) * 128; }
            else                { pS = whh3 + (size_t)(g * 64 + uu) * 64;
                                  pL = wih3 + (size_t)(g * 64 + uu) * 128; }
            #pragma unroll
            for (int ks = 0; ks < 2; ++ks) {
                const float4 v0 = *(const float4*)(pS + ks * 32 + kq);
                const float4 v1 = *(const float4*)(pS + ks * 32 + kq + 4);
                short8 b;
                b[0] = (short)f2bf(v0.x); b[1] = (short)f2bf(v0.y);
                b[2] = (short)f2bf(v0.z); b[3] = (short)f2bf(v0.w);
                b[4] = (short)f2bf(v1.x); b[5] = (short)f2bf(v1.y);
                b[6] = (short)f2bf(v1.z); b[7] = (short)f2bf(v1.w);
                bregS[ut][g][ks] = b;
            }
            if (role >= 2) {
                #pragma unroll
                for (int ks = 0; ks < 4; ++ks) {
                    const float4 v0 = *(const float4*)(pL + ks * 32 + kq);
                    const float4 v1 = *(const float4*)(pL + ks * 32 + kq + 4);
                    short8 b;
                    b[0] = (short)f2bf(v0.x); b[1] = (short)f2bf(v0.y);
                    b[2] = (short)f2bf(v0.z); b[3] = (short)f2bf(v0.w);
                    b[4] = (short)f2bf(v1.x); b[5] = (short)f2bf(v1.y);
                    b[6] = (short)f2bf(v1.z); b[7] = (short)f2bf(v1.w);
                    bregL[ut][g][ks] = b;
                }
            }
        }

    // bias for this thread's single cell item (unit tile = hi>>1)
    const int itile = hi >> 1;
    const int row   = hi & 1;
    const int uloc  = itile * 16 + fr;
    const int unit  = ubase + uloc;
    float bias[4];
    {
        const float* bihp = (role == 1) ? bih1 : (role == 2) ? bih2 : bih3;
        const float* bhhp = (role == 1) ? bhh1 : (role == 2) ? bhh2 : bhh3;
        #pragma unroll
        for (int g = 0; g < 4; ++g)
            bias[g] = bihp[g * Hl + unit] + bhhp[g * Hl + unit];
    }

    for (int i = tid; i < 16 * 64; i += 512) {
        h1sh[0][i] = 0; h1sh[1][i] = 0;
        h3sh[0][i] = 0; h3sh[1][i] = 0;
    }
    for (int i = tid; i < 16 * 128; i += 512) { h2sh[0][i] = 0; h2sh[1][i] = 0; }

    // stage xg(t=0): 2 rows x 256 ushorts
    if (tid < 64) {
        const int rw = tid >> 5, xc = (tid & 31) * 8;
        *(short8*)&xsh[0][rw * 256 + xc] =
            *(const short8*)(xg1 + ((size_t)(r0 + rw) * Tn) * 256 + xc);
    }

    float c = 0.f;
    __syncthreads();

    const int nSteps = Tn + 2;            // 66
    for (int s = 0; s < nSteps; ++s) {
        const int rb = s & 1, wb = rb ^ 1;

        // xg(s+1) -> xsh[wb]: one GLD16 by wave 0 (2 rows x 512B contiguous)
        if (wid == 0 && s + 1 < Tn) {
            GLD16(xg1 + ((size_t)(r0 + (lane >> 5)) * Tn + (s + 1)) * 256
                      + (lane & 31) * 8,
                  &xsh[wb][0]);
        }

        const bool act = (role == 1) ? (s < Tn)
                       : (role == 2) ? (s >= 1 && s <= Tn)
                                     : (s >= 2 && s <= Tn + 1);
        if (act) {
            short8 aS[2], aL[4];
            const ushort_t* srcS = (role == 3) ? h3sh[rb] : h1sh[rb];
            #pragma unroll
            for (int ks = 0; ks < 2; ++ks) {
                const int k0 = ks * 32 + kq;
                aS[ks] = *(const short8*)&srcS[fr * 64 + (k0 ^ ((fr & 7) << 3))];
            }
            if (role >= 2) {
                #pragma unroll
                for (int ks = 0; ks < 4; ++ks) {
                    const int k0 = ks * 32 + kq;
                    aL[ks] = *(const short8*)
                        &h2sh[rb][fr * 128 + (k0 ^ ((fr & 7) << 3))];
                }
            }

            #pragma unroll
            for (int ut = 0; ut < 2; ++ut)
                #pragma unroll
                for (int g = 0; g < 4; ++g) {
                    f32x4 acc = {};
                    #pragma unroll
                    for (int ks = 0; ks < 2; ++ks)
                        acc = __builtin_amdgcn_mfma_f32_16x16x32_bf16(
                            aS[ks], bregS[ut][g][ks], acc, 0, 0, 0);
                    if (role >= 2) {
                        #pragma unroll
                        for (int ks = 0; ks < 4; ++ks)
                            acc = __builtin_amdgcn_mfma_f32_16x16x32_bf16(
                                aL[ks], bregL[ut][g][ks], acc, 0, 0, 0);
                    }
                    if (hi == 0)
                        *(f32x4*)&gsw[wid][(g * 32 + ut * 16 + fr) * 4] = acc;
                }

            // cell update: 1 item/thread (row = hi&1, unit tile = hi>>1)
            {
                float gi = gsw[wid][(0 * 32 + uloc) * 4 + row] + bias[0];
                float gf = gsw[wid][(1 * 32 + uloc) * 4 + row] + bias[1];
                float gg = gsw[wid][(2 * 32 + uloc) * 4 + row] + bias[2];
                float go = gsw[wid][(3 * 32 + uloc) * 4 + row] + bias[3];
                if (role == 1) {
                    const ushort_t* xb = &xsh[rb][row * 256 + unit];
                    gi += bf2f(xb[0]);   gf += bf2f(xb[64]);
                    gg += bf2f(xb[128]); go += bf2f(xb[192]);
                }
                const float iv = sigmoid_f(gi);
                const float fv = sigmoid_f(gf);
                const float gv = tanh_f(gg);
                const float ov = sigmoid_f(go);
                c = fmaf(fv, c, iv * gv);
                const float h = ov * tanh_f(c);
                ushort_t* hdst = (role == 1) ? h1sh[wb]
                               : (role == 2) ? h2sh[wb] : h3sh[wb];
                hdst[row * Hl + (unit ^ (row << 3))] = f2bf(h);
                if (role == 3 && s == Tn + 1)
                    hlast[(size_t)(r0 + row) * 64 + unit] = h;
            }
        }
        __syncthreads();      // h(wb) + xsh[wb] (GLD16 drained) visible
    }
}

// ---------------------------------------------------------------------------
// FC head: hlast[B,64] -> fc1 relu -> fc2 relu -> fc3 -> softmax
// ---------------------------------------------------------------------------
__global__ __launch_bounds__(256) void head_kernel(
    const float* __restrict__ hlast,
    const float* __restrict__ w1, const float* __restrict__ b1,
    const float* __restrict__ w2, const float* __restrict__ b2,
    const float* __restrict__ w3, const float* __restrict__ b3,
    float* __restrict__ out)
{
    __shared__ float W1[64][64];
    __shared__ float W2[32][64];
    __shared__ float W3[3][32];
    __shared__ float hin[16][64];
    __shared__ float a1[16][64];
    __shared__ float a2[16][32];
    __shared__ float lg[16][3];

    const int tid = threadIdx.x;
    const int r0 = blockIdx.x * 16;

    for (int i = tid; i < 64 * 64; i += 256) W1[i >> 6][i & 63] = w1[i];
    for (int i = tid; i < 32 * 64; i += 256) W2[i >> 6][i & 63] = w2[i];
    for (int i = tid; i < 3 * 32; i += 256) W3[i >> 5][i & 31] = w3[i];
    for (int i = tid; i < 16 * 64; i += 256) {
        int r = i >> 6, u = i & 63;
        hin[r][u] = hlast[(size_t)(r0 + r) * 64 + u];
    }
    __syncthreads();

    for (int i = tid; i < 16 * 64; i += 256) {
        int r = i >> 6, j = i & 63;
        float s = b1[j];
        #pragma unroll
        for (int k = 0; k < 64; ++k) s = fmaf(hin[r][k], W1[j][k], s);
        a1[r][j] = fmaxf(s, 0.f);
    }
    __syncthreads();

    for (int i = tid; i < 16 * 32; i += 256) {
        int r = i >> 5, j = i & 31;
        float s = b2[j];
        #pragma unroll
        for (int k = 0; k < 64; ++k) s = fmaf(a1[r][k], W2[j][k], s);
        a2[r][j] = fmaxf(s, 0.f);
    }
    __syncthreads();

    for (int i = tid; i < 16 * 3; i += 256) {
        int r = i / 3, j = i % 3;
        float s = b3[j];
        #pragma unroll
        for (int k = 0; k < 32; ++k) s = fmaf(a2[r][k], W3[j][k], s);
        lg[r][j] = s;
    }
    __syncthreads();

    if (tid < 16) {
        float l0 = lg[tid][0], l1 = lg[tid][1], l2 = lg[tid][2];
        float m = fmaxf(l0, fmaxf(l1, l2));
        float e0 = __expf(l0 - m), e1 = __expf(l1 - m), e2 = __expf(l2 - m);
        float inv = 1.0f / (e0 + e1 + e2);
        out[(size_t)(r0 + tid) * 3 + 0] = e0 * inv;
        out[(size_t)(r0 + tid) * 3 + 1] = e1 * inv;
        out[(size_t)(r0 + tid) * 3 + 2] = e2 * inv;
    }
}

// ---------------------------------------------------------------------------
extern "C" void kernel_launch(void* const* d_in, const int* in_sizes, int n_in,
                              void* d_out, int out_size, void* d_ws, size_t ws_size,
                              hipStream_t stream)
{
    const float* x    = (const float*)d_in[0];
    const float* wih1 = (const float*)d_in[1];
    const float* whh1 = (const float*)d_in[2];
    const float* bih1 = (const float*)d_in[3];
    const float* bhh1 = (const float*)d_in[4];
    const float* wih2 = (const float*)d_in[5];
    const float* whh2 = (const float*)d_in[6];
    const float* bih2 = (const float*)d_in[7];
    const float* bhh2 = (const float*)d_in[8];
    const float* wih3 = (const float*)d_in[9];
    const float* whh3 = (const float*)d_in[10];
    const float* bih3 = (const float*)d_in[11];
    const float* bhh3 = (const float*)d_in[12];
    const float* f1w  = (const float*)d_in[13];
    const float* f1b  = (const float*)d_in[14];
    const float* f2w  = (const float*)d_in[15];
    const float* f2b  = (const float*)d_in[16];
    const float* f3w  = (const float*)d_in[17];
    const float* f3b  = (const float*)d_in[18];
    float* outp = (float*)d_out;

    // workspace layout (~35 MB):
    //   bufA : 33,554,432 B  (bf16 [M,256]: xg1)
    //   hlast:    262,144 B  (fp32 [B,64])
    //   w1b  : bf16 w_ih1 (~0.9 MB)
    char* wsb = (char*)d_ws;
    size_t off = 0;
    ushort_t* bufA  = (ushort_t*)(wsb + off); off += 33554432;
    float*    hlast = (float*)(wsb + off);    off += 262144;
    ushort_t* w1b   = (ushort_t*)(wsb + off);

    const int T = T_SZ;

    convert_w1<<<208, 256, 0, stream>>>(wih1, w1b);

    // Layer 1 input GEMM (BM=128; 2 blocks/CU)
    gemm_l1<<<M_SZ / 128, 512, 0, stream>>>(x, w1b, bufA);

    // All three LSTM layers; 2 batch rows/block -> 2 blocks/CU overlap
    lstm3_gg<<<B_SZ / 2, 512, 0, stream>>>(
        bufA, whh1, bih1, bhh1,
        wih2, whh2, bih2, bhh2,
        wih3, whh3, bih3, bhh3,
        hlast, T);

    // Head
    head_kernel<<<B_SZ / 16, 256, 0, stream>>>(
        hlast, f1w, f1b, f2w, f2b, f3w, f3b, outp);
}

// Round 24
// 336.840 us; speedup vs baseline: 1.3340x; 1.3340x over previous
//
#include <hip/hip_runtime.h>
#include <hip/hip_bf16.h>

#define B_SZ   1024
#define T_SZ   64
#define D_IN   1662
#define D_INP  1664                 // padded to 32-multiple
#define M_SZ   (B_SZ * T_SZ)        // 65536

typedef __attribute__((ext_vector_type(8))) short short8;
typedef __attribute__((ext_vector_type(4))) float f32x4;
typedef unsigned short ushort_t;

// fp32 -> bf16 round-to-nearest-even (finite inputs)
__device__ __forceinline__ unsigned short f2bf(float f) {
    unsigned u = __builtin_bit_cast(unsigned, f);
    u += 0x7FFFu + ((u >> 16) & 1u);
    return (unsigned short)(u >> 16);
}
__device__ __forceinline__ float bf2f(ushort_t u) {
    return __builtin_bit_cast(float, (unsigned)u << 16);
}

// async global->LDS, 16B per lane, dest = wave-uniform base + lane*16
#define GLD16(gp, lp) __builtin_amdgcn_global_load_lds(                        \
    (const __attribute__((address_space(1))) void*)(gp),                       \
    (__attribute__((address_space(3))) void*)(lp), 16, 0, 0)

__device__ __forceinline__ float sigmoid_f(float x) {
    return 1.0f / (1.0f + __expf(-x));
}
__device__ __forceinline__ float tanh_f(float x) {
    float a = fabsf(x);
    float e = __expf(2.0f * a);
    float r = 1.0f - 2.0f / (e + 1.0f);
    return copysignf(r, x);
}

// ---------------------------------------------------------------------------
// convert fp32 [256,1662] -> bf16 [256,1664] (w_ih1 only; zero-pads cols)
// ---------------------------------------------------------------------------
__global__ __launch_bounds__(256) void convert_w1(
    const float* __restrict__ src, ushort_t* __restrict__ dst)
{
    constexpr int cpr = D_INP >> 3;
    const int total = 256 * cpr;
    const int stride = gridDim.x * blockDim.x;
    for (int idx = blockIdx.x * blockDim.x + threadIdx.x;
         idx < total; idx += stride) {
        const int row  = idx / cpr;
        const int base = (idx % cpr) << 3;
        const float* s = src + (size_t)row * D_IN;
        short8 o;
        #pragma unroll
        for (int j = 0; j < 4; ++j) {
            const int k = base + 2 * j;
            float2 v = make_float2(0.f, 0.f);
            if (k < D_IN) v = *(const float2*)(s + k);
            o[2 * j]     = (short)f2bf(v.x);
            o[2 * j + 1] = (short)f2bf(v.y);
        }
        *(short8*)(dst + (size_t)row * D_INP + base) = o;
    }
}

// ---------------------------------------------------------------------------
// Layer-1 GEMM — BM=128 (r20/r22 best-known configuration):
// out[M,256]bf16 = A[M,K]fp32 @ W[256,Kp]bf16^T.
// 128x256 tile, BK=32, 512 threads (8 waves, 2x4), grid M/128=512 ->
// 2 blocks/CU. Per iteration each block stages W ONCE for 128 M-rows.
// ---------------------------------------------------------------------------
__global__ __launch_bounds__(512, 2) void gemm_l1(
    const float* __restrict__ A, const ushort_t* __restrict__ W,
    ushort_t* __restrict__ out)
{
    constexpr int K = D_IN, Kp = D_INP, G = 256;
    __shared__ __align__(16) ushort_t As[128 * 32];     //  8 KB
    __shared__ __align__(16) ushort_t Ws[256 * 32];     // 16 KB

    const int tid = threadIdx.x, lane = tid & 63, wid = tid >> 6;
    const int wr = wid >> 2, wc = wid & 3;        // 2x4 wave grid
    const int m0 = blockIdx.x * 128;

    // A staging: row tid>>2 (0..127), 8 fp32 (4x float2) at col (tid&3)*8
    const int arow  = tid >> 2;
    const int acolb = (tid & 3) * 8;
    const float* Abase = A + (size_t)(m0 + arow) * K + acolb;

    // W staging: wave wid stages rows wid*32..+31 in 2 GLD16 chunks of 16
    const size_t wlofs = (size_t)(lane >> 2) * Kp + (lane & 3) * 8;
    const ushort_t* Wg0 = W + (size_t)(wid * 32) * Kp + wlofs;
    const ushort_t* Wg1 = Wg0 + (size_t)16 * Kp;
    ushort_t* lw0 = &Ws[(wid * 32) * 32];
    ushort_t* lw1 = lw0 + 16 * 32;

    const int fr = lane & 15, kq = (lane >> 4) * 8;

    f32x4 acc[4][4] = {};
    const int nFull = K / 32;                 // 51 full iters + 1 tail

    float2 av[4];
    #pragma unroll
    for (int j = 0; j < 4; ++j) av[j] = *(const float2*)(Abase + 2 * j);

    for (int it = 0; it <= nFull; ++it) {
        const int k0 = it * 32;
        __syncthreads();                      // prev iter LDS reads done
        GLD16(Wg0 + k0, lw0); GLD16(Wg1 + k0, lw1);
        short8 pk;
        #pragma unroll
        for (int j = 0; j < 4; ++j) {
            pk[2 * j]     = (short)f2bf(av[j].x);
            pk[2 * j + 1] = (short)f2bf(av[j].y);
        }
        *(short8*)&As[arow * 32 + acolb] = pk;
        __syncthreads();                      // staging (incl vmcnt) done

        // prefetch A for it+1 (hides under MFMA below)
        if (it < nFull) {
            const int kn = (it + 1) * 32;
            if (it + 1 < nFull) {
                #pragma unroll
                for (int j = 0; j < 4; ++j)
                    av[j] = *(const float2*)(Abase + kn + 2 * j);
            } else {
                #pragma unroll
                for (int j = 0; j < 4; ++j) {
                    const int kk = kn + acolb + 2 * j;
                    av[j] = (kk < K) ? *(const float2*)(Abase + kn + 2 * j)
                                     : make_float2(0.f, 0.f);
                }
            }
        }

        short8 af[4], bfr[4];
        #pragma unroll
        for (int fm = 0; fm < 4; ++fm)
            af[fm] = *(const short8*)&As[(wr * 64 + fm * 16 + fr) * 32 + kq];
        #pragma unroll
        for (int fn = 0; fn < 4; ++fn)
            bfr[fn] = *(const short8*)&Ws[(wc * 64 + fn * 16 + fr) * 32 + kq];
        #pragma unroll
        for (int fm = 0; fm < 4; ++fm)
            #pragma unroll
            for (int fn = 0; fn < 4; ++fn)
                acc[fm][fn] = __builtin_amdgcn_mfma_f32_16x16x32_bf16(
                    af[fm], bfr[fn], acc[fm][fn], 0, 0, 0);
    }

    // epilogue: bf16, no bias. C/D: col=lane&15, row=(lane>>4)*4+j
    const int rbase = (lane >> 4) * 4;
    #pragma unroll
    for (int fn = 0; fn < 4; ++fn) {
        const int g = wc * 64 + fn * 16 + fr;
        #pragma unroll
        for (int fm = 0; fm < 4; ++fm) {
            const int mbase = m0 + wr * 64 + fm * 16 + rbase;
            #pragma unroll
            for (int j = 0; j < 4; ++j)
                out[(size_t)(mbase + j) * G + g] = f2bf(acc[fm][fn][j]);
        }
    }
}

// ---------------------------------------------------------------------------
// Pipelined 3-layer LSTM, gate-grouped, one barrier per step (r14/r22 form:
// 4 batch rows/block, grid B/4 = 256).
// ---------------------------------------------------------------------------
__global__ __launch_bounds__(512, 2) void lstm3_gg(
    const ushort_t* __restrict__ xg1,   // [B,T,256] bf16 (no bias)
    const float* __restrict__ whh1,
    const float* __restrict__ bih1, const float* __restrict__ bhh1,
    const float* __restrict__ wih2, const float* __restrict__ whh2,
    const float* __restrict__ bih2, const float* __restrict__ bhh2,
    const float* __restrict__ wih3, const float* __restrict__ whh3,
    const float* __restrict__ bih3, const float* __restrict__ bhh3,
    float* __restrict__ hlast, int Tn)  // [B,64]
{
    __shared__ ushort_t h1sh[2][16 * 64];
    __shared__ ushort_t h2sh[2][16 * 128];
    __shared__ ushort_t h3sh[2][16 * 64];
    __shared__ __align__(16) ushort_t xsh[2][1024];   // 4 rows x 256
    __shared__ __align__(16) float gsw[8][128 * 4];   // per-wave gate frags

    const int tid = threadIdx.x, lane = tid & 63, wid = tid >> 6;
    const int r0 = blockIdx.x * 4;
    const int fr = lane & 15, hi = lane >> 4, kq = hi * 8;

    int role, ubase, Hl;
    if (wid < 2)      { role = 1; ubase = wid * 32;       Hl = 64; }
    else if (wid < 6) { role = 2; ubase = (wid - 2) * 32; Hl = 128; }
    else              { role = 3; ubase = (wid - 6) * 32; Hl = 64; }

    short8 bregS[2][4][2];
    short8 bregL[2][4][4];
    #pragma unroll
    for (int ut = 0; ut < 2; ++ut)
        #pragma unroll
        for (int g = 0; g < 4; ++g) {
            const int uu = ubase + ut * 16 + fr;
            const float *pS, *pL = nullptr;
            if (role == 1)      { pS = whh1 + (size_t)(g * 64 + uu) * 64; }
            else if (role == 2) { pS = wih2 + (size_t)(g * 128 + uu) * 64;
                                  pL = whh2 + (size_t)(g * 128 + uu) * 128; }
            else                { pS = whh3 + (size_t)(g * 64 + uu) * 64;
                                  pL = wih3 + (size_t)(g * 64 + uu) * 128; }
            #pragma unroll
            for (int ks = 0; ks < 2; ++ks) {
                const float4 v0 = *(const float4*)(pS + ks * 32 + kq);
                const float4 v1 = *(const float4*)(pS + ks * 32 + kq + 4);
                short8 b;
                b[0] = (short)f2bf(v0.x); b[1] = (short)f2bf(v0.y);
                b[2] = (short)f2bf(v0.z); b[3] = (short)f2bf(v0.w);
                b[4] = (short)f2bf(v1.x); b[5] = (short)f2bf(v1.y);
                b[6] = (short)f2bf(v1.z); b[7] = (short)f2bf(v1.w);
                bregS[ut][g][ks] = b;
            }
            if (role >= 2) {
                #pragma unroll
                for (int ks = 0; ks < 4; ++ks) {
                    const float4 v0 = *(const float4*)(pL + ks * 32 + kq);
                    const float4 v1 = *(const float4*)(pL + ks * 32 + kq + 4);
                    short8 b;
                    b[0] = (short)f2bf(v0.x); b[1] = (short)f2bf(v0.y);
                    b[2] = (short)f2bf(v0.z); b[3] = (short)f2bf(v0.w);
                    b[4] = (short)f2bf(v1.x); b[5] = (short)f2bf(v1.y);
                    b[6] = (short)f2bf(v1.z); b[7] = (short)f2bf(v1.w);
                    bregL[ut][g][ks] = b;
                }
            }
        }

    float bias[2][4];
    {
        const float* bihp = (role == 1) ? bih1 : (role == 2) ? bih2 : bih3;
        const float* bhhp = (role == 1) ? bhh1 : (role == 2) ? bhh2 : bhh3;
        #pragma unroll
        for (int i = 0; i < 2; ++i) {
            const int unit = ubase + i * 16 + fr;
            #pragma unroll
            for (int g = 0; g < 4; ++g)
                bias[i][g] = bihp[g * Hl + unit] + bhhp[g * Hl + unit];
        }
    }

    for (int i = tid; i < 16 * 64; i += 512) {
        h1sh[0][i] = 0; h1sh[1][i] = 0;
        h3sh[0][i] = 0; h3sh[1][i] = 0;
    }
    for (int i = tid; i < 16 * 128; i += 512) { h2sh[0][i] = 0; h2sh[1][i] = 0; }

    if (tid < 128) {
        const int rw = tid >> 5, xc = (tid & 31) * 8;
        *(short8*)&xsh[0][rw * 256 + xc] =
            *(const short8*)(xg1 + ((size_t)(r0 + rw) * Tn) * 256 + xc);
    }

    float c[2] = {0.f, 0.f};
    __syncthreads();

    const int nSteps = Tn + 2;            // 66
    for (int s = 0; s < nSteps; ++s) {
        const int rb = s & 1, wb = rb ^ 1;

        if (wid < 2 && s + 1 < Tn) {
            const int rw = wid * 2 + (lane >> 5);
            const int xc = (lane & 31) * 8;
            GLD16(xg1 + ((size_t)(r0 + rw) * Tn + (s + 1)) * 256 + xc,
                  &xsh[wb][wid * 512]);
        }

        const bool act = (role == 1) ? (s < Tn)
                       : (role == 2) ? (s >= 1 && s <= Tn)
                                     : (s >= 2 && s <= Tn + 1);
        if (act) {
            short8 aS[2], aL[4];
            const ushort_t* srcS = (role == 3) ? h3sh[rb] : h1sh[rb];
            #pragma unroll
            for (int ks = 0; ks < 2; ++ks) {
                const int k0 = ks * 32 + kq;
                aS[ks] = *(const short8*)&srcS[fr * 64 + (k0 ^ ((fr & 7) << 3))];
            }
            if (role >= 2) {
                #pragma unroll
                for (int ks = 0; ks < 4; ++ks) {
                    const int k0 = ks * 32 + kq;
                    aL[ks] = *(const short8*)
                        &h2sh[rb][fr * 128 + (k0 ^ ((fr & 7) << 3))];
                }
            }

            #pragma unroll
            for (int ut = 0; ut < 2; ++ut)
                #pragma unroll
                for (int g = 0; g < 4; ++g) {
                    f32x4 acc = {};
                    #pragma unroll
                    for (int ks = 0; ks < 2; ++ks)
                        acc = __builtin_amdgcn_mfma_f32_16x16x32_bf16(
                            aS[ks], bregS[ut][g][ks], acc, 0, 0, 0);
                    if (role >= 2) {
                        #pragma unroll
                        for (int ks = 0; ks < 4; ++ks)
                            acc = __builtin_amdgcn_mfma_f32_16x16x32_bf16(
                                aL[ks], bregL[ut][g][ks], acc, 0, 0, 0);
                    }
                    if (hi == 0)
                        *(f32x4*)&gsw[wid][(g * 32 + ut * 16 + fr) * 4] = acc;
                }

            #pragma unroll
            for (int i = 0; i < 2; ++i) {
                const int uloc = i * 16 + fr;
                const int unit = ubase + uloc;
                float gi = gsw[wid][(0 * 32 + uloc) * 4 + hi] + bias[i][0];
                float gf = gsw[wid][(1 * 32 + uloc) * 4 + hi] + bias[i][1];
                float gg = gsw[wid][(2 * 32 + uloc) * 4 + hi] + bias[i][2];
                float go = gsw[wid][(3 * 32 + uloc) * 4 + hi] + bias[i][3];
                if (role == 1) {
                    const ushort_t* xb = &xsh[rb][hi * 256 + unit];
                    gi += bf2f(xb[0]);   gf += bf2f(xb[64]);
                    gg += bf2f(xb[128]); go += bf2f(xb[192]);
                }
                const float iv = sigmoid_f(gi);
                const float fv = sigmoid_f(gf);
                const float gv = tanh_f(gg);
                const float ov = sigmoid_f(go);
                c[i] = fmaf(fv, c[i], iv * gv);
                const float h = ov * tanh_f(c[i]);
                ushort_t* hdst = (role == 1) ? h1sh[wb]
                               : (role == 2) ? h2sh[wb] : h3sh[wb];
                hdst[hi * Hl + (unit ^ (hi << 3))] = f2bf(h);
                if (role == 3 && s == Tn + 1)
                    hlast[(size_t)(r0 + hi) * 64 + unit] = h;
            }
        }
        __syncthreads();      // h(wb) + xsh[wb] (GLD16 drained) visible
    }
}

// ---------------------------------------------------------------------------
// FC head: hlast[B,64] -> fc1 relu -> fc2 relu -> fc3 -> softmax
// ---------------------------------------------------------------------------
__global__ __launch_bounds__(256) void head_kernel(
    const float* __restrict__ hlast,
    const float* __restrict__ w1, const float* __restrict__ b1,
    const float* __restrict__ w2, const float* __restrict__ b2,
    const float* __restrict__ w3, const float* __restrict__ b3,
    float* __restrict__ out)
{
    __shared__ float W1[64][64];
    __shared__ float W2[32][64];
    __shared__ float W3[3][32];
    __shared__ float hin[16][64];
    __shared__ float a1[16][64];
    __shared__ float a2[16][32];
    __shared__ float lg[16][3];

    const int tid = threadIdx.x;
    const int r0 = blockIdx.x * 16;

    for (int i = tid; i < 64 * 64; i += 256) W1[i >> 6][i & 63] = w1[i];
    for (int i = tid; i < 32 * 64; i += 256) W2[i >> 6][i & 63] = w2[i];
    for (int i = tid; i < 3 * 32; i += 256) W3[i >> 5][i & 31] = w3[i];
    for (int i = tid; i < 16 * 64; i += 256) {
        int r = i >> 6, u = i & 63;
        hin[r][u] = hlast[(size_t)(r0 + r) * 64 + u];
    }
    __syncthreads();

    for (int i = tid; i < 16 * 64; i += 256) {
        int r = i >> 6, j = i & 63;
        float s = b1[j];
        #pragma unroll
        for (int k = 0; k < 64; ++k) s = fmaf(hin[r][k], W1[j][k], s);
        a1[r][j] = fmaxf(s, 0.f);
    }
    __syncthreads();

    for (int i = tid; i < 16 * 32; i += 256) {
        int r = i >> 5, j = i & 31;
        float s = b2[j];
        #pragma unroll
        for (int k = 0; k < 64; ++k) s = fmaf(a1[r][k], W2[j][k], s);
        a2[r][j] = fmaxf(s, 0.f);
    }
    __syncthreads();

    for (int i = tid; i < 16 * 3; i += 256) {
        int r = i / 3, j = i % 3;
        float s = b3[j];
        #pragma unroll
        for (int k = 0; k < 32; ++k) s = fmaf(a2[r][k], W3[j][k], s);
        lg[r][j] = s;
    }
    __syncthreads();

    if (tid < 16) {
        float l0 = lg[tid][0], l1 = lg[tid][1], l2 = lg[tid][2];
        float m = fmaxf(l0, fmaxf(l1, l2));
        float e0 = __expf(l0 - m), e1 = __expf(l1 - m), e2 = __expf(l2 - m);
        float inv = 1.0f / (e0 + e1 + e2);
        out[(size_t)(r0 + tid) * 3 + 0] = e0 * inv;
        out[(size_t)(r0 + tid) * 3 + 1] = e1 * inv;
        out[(size_t)(r0 + tid) * 3 + 2] = e2 * inv;
    }
}

// ---------------------------------------------------------------------------
extern "C" void kernel_launch(void* const* d_in, const int* in_sizes, int n_in,
                              void* d_out, int out_size, void* d_ws, size_t ws_size,
                              hipStream_t stream)
{
    const float* x    = (const float*)d_in[0];
    const float* wih1 = (const float*)d_in[1];
    const float* whh1 = (const float*)d_in[2];
    const float* bih1 = (const float*)d_in[3];
    const float* bhh1 = (const float*)d_in[4];
    const float* wih2 = (const float*)d_in[5];
    const float* whh2 = (const float*)d_in[6];
    const float* bih2 = (const float*)d_in[7];
    const float* bhh2 = (const float*)d_in[8];
    const float* wih3 = (const float*)d_in[9];
    const float* whh3 = (const float*)d_in[10];
    const float* bih3 = (const float*)d_in[11];
    const float* bhh3 = (const float*)d_in[12];
    const float* f1w  = (const float*)d_in[13];
    const float* f1b  = (const float*)d_in[14];
    const float* f2w  = (const float*)d_in[15];
    const float* f2b  = (const float*)d_in[16];
    const float* f3w  = (const float*)d_in[17];
    const float* f3b  = (const float*)d_in[18];
    float* outp = (float*)d_out;

    // workspace layout (~35 MB):
    //   bufA : 33,554,432 B  (bf16 [M,256]: xg1)
    //   hlast:    262,144 B  (fp32 [B,64])
    //   w1b  : bf16 w_ih1 (~0.9 MB)
    char* wsb = (char*)d_ws;
    size_t off = 0;
    ushort_t* bufA  = (ushort_t*)(wsb + off); off += 33554432;
    float*    hlast = (float*)(wsb + off);    off += 262144;
    ushort_t* w1b   = (ushort_t*)(wsb + off);

    const int T = T_SZ;

    convert_w1<<<208, 256, 0, stream>>>(wih1, w1b);

    // Layer 1 input GEMM (BM=128, W traffic halved; 2 blocks/CU)
    gemm_l1<<<M_SZ / 128, 512, 0, stream>>>(x, w1b, bufA);

    // All three LSTM layers, gate-grouped single-barrier pipeline
    lstm3_gg<<<B_SZ / 4, 512, 0, stream>>>(
        bufA, whh1, bih1, bhh1,
        wih2, whh2, bih2, bhh2,
        wih3, whh3, bih3, bhh3,
        hlast, T);

    // Head
    head_kernel<<<B_SZ / 16, 256, 0, stream>>>(
        hlast, f1w, f1b, f2w, f2b, f3w, f3b, outp);
}